// Round 10
// baseline (292.893 us; speedup 1.0000x reference)
//
#include <hip/hip_runtime.h>

// Sparse 3D conv (Cin=1, Cout=16), stride-2 — parity-split, fused rulebook
// pass + accumulating reduce.
//
// Order: out = 0; fused_scatter {dense->g planes, sparse->atomicAdd out};
//        reduce8 {out[o,:] += sum_p g[p][o]*W[k(p),:]}  (RMW, preserves
//        the sparse contributions already in out).
//
// Round-7 lesson: no global compaction counter (LDS counter instead).
// Round-6 lesson: sparse atomics 16-lanes-per-entry (one 64B line).
// Round-8/9 lesson: 4 entries/thread for MLP; int4 idx loads.

typedef float vf4 __attribute__((ext_vector_type(4)));
typedef int   vi4 __attribute__((ext_vector_type(4)));

__device__ inline unsigned short f32_to_bf16_rne(float x) {
    unsigned int u = __float_as_uint(x);
    unsigned int r = 0x7FFFu + ((u >> 16) & 1u);
    return (unsigned short)((u + r) >> 16);
}

__device__ inline int dense_plane(int k) {   // -1 if sparse
    int a = k / 9, b = (k / 3) % 3, c = k % 3;
    if (a == 0 || b == 0 || c == 0) return -1;
    return ((a - 1) << 2) | ((b - 1) << 1) | (c - 1);
}

__global__ void __launch_bounds__(256)
fused_scatter(const float* __restrict__ feats,
              const float* __restrict__ weight,
              const int* __restrict__ in_idx,
              const int* __restrict__ out_idx,
              const int* __restrict__ k_idx,
              unsigned short* __restrict__ g,
              float* __restrict__ out,
              int M, int np) {
    __shared__ int sl[1024];
    __shared__ int sc;
    if (threadIdx.x == 0) sc = 0;
    __syncthreads();

    int t = blockIdx.x * blockDim.x + threadIdx.x;
    int base = t * 4;
    if (base + 3 < M) {
        vi4 kk = *(const vi4*)&k_idx[base];
        vi4 ii = *(const vi4*)&in_idx[base];
        vi4 oo = *(const vi4*)&out_idx[base];
        int p0 = dense_plane(kk.x), p1 = dense_plane(kk.y),
            p2 = dense_plane(kk.z), p3 = dense_plane(kk.w);
        float f0 = feats[ii.x], f1 = feats[ii.y],
              f2 = feats[ii.z], f3 = feats[ii.w];
        if (p0 >= 0) g[(size_t)p0 * np + oo.x] = f32_to_bf16_rne(f0);
        else         sl[atomicAdd(&sc, 1)] = base + 0;
        if (p1 >= 0) g[(size_t)p1 * np + oo.y] = f32_to_bf16_rne(f1);
        else         sl[atomicAdd(&sc, 1)] = base + 1;
        if (p2 >= 0) g[(size_t)p2 * np + oo.z] = f32_to_bf16_rne(f2);
        else         sl[atomicAdd(&sc, 1)] = base + 2;
        if (p3 >= 0) g[(size_t)p3 * np + oo.w] = f32_to_bf16_rne(f3);
        else         sl[atomicAdd(&sc, 1)] = base + 3;
    } else if (base < M) {
        for (int m = base; m < M; ++m) {
            int p = dense_plane(k_idx[m]);
            if (p >= 0)
                g[(size_t)p * np + out_idx[m]] =
                    f32_to_bf16_rne(feats[in_idx[m]]);
            else
                sl[atomicAdd(&sc, 1)] = m;
        }
    }
    __syncthreads();

    int nsp = sc;
    int grp = threadIdx.x >> 4;
    int c   = threadIdx.x & 15;
    for (int e = grp; e < nsp; e += 16) {
        int m = sl[e];
        int k = k_idx[m];
        float f = feats[in_idx[m]];
        atomicAdd(out + (long long)out_idx[m] * 16 + c,
                  f * weight[k * 16 + c]);   // exact f32, zeroed out
    }
}

__global__ void __launch_bounds__(256, 4)
reduce8(const unsigned int* __restrict__ g32,
        const float* __restrict__ weight,
        float* __restrict__ out,
        int n_out, int half_np) {
    int t = blockIdx.x * blockDim.x + threadIdx.x;
    int o0 = t * 2;
    if (o0 >= n_out) return;

    unsigned int gu[8];
    #pragma unroll
    for (int p = 0; p < 8; ++p)
        gu[p] = g32[(size_t)p * half_np + t];

    vf4 a0 = {0,0,0,0}, a1 = a0, a2 = a0, a3 = a0;
    vf4 b0 = a0, b1 = a0, b2 = a0, b3 = a0;
    const int KP[8] = {13, 14, 16, 17, 22, 23, 25, 26};
    #pragma unroll
    for (int p = 0; p < 8; ++p) {
        const vf4* w = (const vf4*)&weight[KP[p] * 16];
        vf4 w0 = w[0], w1 = w[1], w2 = w[2], w3 = w[3];
        float fa = __uint_as_float(gu[p] << 16);
        float fb = __uint_as_float(gu[p] & 0xFFFF0000u);
        a0 += fa * w0; a1 += fa * w1; a2 += fa * w2; a3 += fa * w3;
        b0 += fb * w0; b1 += fb * w1; b2 += fb * w2; b3 += fb * w3;
    }

    vf4* op = (vf4*)(out + (size_t)o0 * 16);
    // RMW: preserve sparse atomics already accumulated in out.
    op[0] += a0; op[1] += a1; op[2] += a2; op[3] += a3;
    if (o0 + 1 < n_out) {
        op[4] += b0; op[5] += b1; op[6] += b2; op[7] += b3;
    }
}

// ---- fallback path (ws too small): known-correct atomic scatter ----
__global__ void __launch_bounds__(256)
sparse_conv_scatter_atomic(const float* __restrict__ feats,
                           const float* __restrict__ weight,
                           const int* __restrict__ in_idx,
                           const int* __restrict__ out_idx,
                           const int* __restrict__ k_idx,
                           float* __restrict__ out,
                           int M) {
    long long t = (long long)blockIdx.x * blockDim.x + threadIdx.x;
    int m = (int)(t >> 4);
    int c = (int)(t & 15);
    if (m >= M) return;
    float f = feats[in_idx[m]];
    float w = weight[k_idx[m] * 16 + c];
    atomicAdd(out + (long long)out_idx[m] * 16 + c, f * w);
}

extern "C" void kernel_launch(void* const* d_in, const int* in_sizes, int n_in,
                              void* d_out, int out_size, void* d_ws, size_t ws_size,
                              hipStream_t stream) {
    const float* feats  = (const float*)d_in[0];
    const float* weight = (const float*)d_in[1];
    const int*   in_idx = (const int*)d_in[2];
    const int*   out_idx= (const int*)d_in[3];
    const int*   k_idx  = (const int*)d_in[4];
    float*       out    = (float*)d_out;

    const int M     = in_sizes[2];
    const int n_out = out_size / 16;
    const int np    = (n_out + 1) & ~1;

    const size_t need = (size_t)8 * (size_t)np * sizeof(unsigned short);
    const int block = 256;

    if (d_ws != nullptr && ws_size >= need) {
        unsigned short* g = (unsigned short*)d_ws;
        hipMemsetAsync(g, 0, need, stream);
        hipMemsetAsync(out, 0, (size_t)out_size * sizeof(float), stream);

        const int nthr1 = (M + 3) / 4;
        const int grid1 = (nthr1 + block - 1) / block;
        fused_scatter<<<grid1, block, 0, stream>>>(feats, weight, in_idx,
                                                   out_idx, k_idx, g, out,
                                                   M, np);

        const int nthr2 = (n_out + 1) / 2;
        const int grid2 = (nthr2 + block - 1) / block;
        reduce8<<<grid2, block, 0, stream>>>((const unsigned int*)g, weight,
                                             out, n_out, np / 2);
    } else {
        hipMemsetAsync(d_out, 0, (size_t)out_size * sizeof(float), stream);
        const long long total = (long long)M * 16;
        const long long grid = (total + block - 1) / block;
        sparse_conv_scatter_atomic<<<(int)grid, block, 0, stream>>>(
            feats, weight, in_idx, out_idx, k_idx, out, M);
    }
}